// Round 12
// baseline (214.442 us; speedup 1.0000x reference)
//
#include <hip/hip_runtime.h>
#include <math.h>

#define HCH   128
#define NMODE 32
#define BB    8
#define LLEN  8192
#define LC    256
#define CCH   (LLEN / LC)      // 32 chunks per row
#define ROWS  (BB * HCH)       // 1024

typedef unsigned int uint;
typedef _Float16 f16x8 __attribute__((ext_vector_type(8)));
typedef float    f32x4 __attribute__((ext_vector_type(4)));

static __device__ __forceinline__ uint pk2(float a, float b) {
    union { _Float16 h[2]; uint u; } v;
    v.h[0] = (_Float16)a; v.h[1] = (_Float16)b;
    return v.u;
}

// branch-free GELU via A&S 7.1.25 erf approx (|err| <= 5e-4)
__device__ __forceinline__ float gelu_f(float y) {
    float z = fabsf(y) * 0.7071067811865476f;
    float p = fmaf(z, 0.078108f, 0.000972f);
    p = fmaf(z, p, 0.230389f);
    p = fmaf(z, p, 0.278393f);
    p = fmaf(z, p, 1.0f);
    float p2 = p * p;
    float p4 = p2 * p2;
    float er = 1.f - __builtin_amdgcn_rcpf(p4);
    float s  = copysignf(er, y);
    return 0.5f * y * (1.f + s);
}

// VALU-pipe cross-lane add (DPP)
#define DPP_ADD(v, ctrl) { int _t = __builtin_amdgcn_update_dpp(0, __float_as_int(v), \
                             (ctrl), 0xF, 0xF, true); (v) += __int_as_float(_t); }

// ---------------- K1: per-h params -> KM table + carry cols (cT) + eT + Wh ----------------
// 256 blocks (2 per h). P[n][t]=w_n^t built in LDS (w^8 recurrence).
// KMrev[i] = km[255-i]; packed as two parity-staggered dword copies so any 2B-aligned
// 8xf16 run is 4 aligned dword reads. Toeplitz block is NEVER materialized.
__global__ __launch_bounds__(256) void k_prep(const float* __restrict__ C_re,
                                              const float* __restrict__ C_im,
                                              const float* __restrict__ logA,
                                              const float* __restrict__ Aim,
                                              const float* __restrict__ logdt,
                                              const float* __restrict__ W,
                                              _Float16* __restrict__ cT,
                                              uint* __restrict__ kmg,
                                              _Float16* __restrict__ eT,
                                              _Float16* __restrict__ Wh,
                                              float* __restrict__ Pw,
                                              float* __restrict__ stats) {
    __shared__ float2 PL[32 * 257];   // P[n][t], row stride 257 (bank-spread)
    __shared__ float4 G01[32];        // (G0r, G0i, G1r, G1i)
    __shared__ float4 HG[32];         // (H0r, H0i, G1r, G1i)
    __shared__ float2 WL[32];         // (wr, wi)
    __shared__ float k0L[256], k1L[256];
    __shared__ _Float16 KMl[516];
    int tid  = threadIdx.x;
    int h    = blockIdx.x >> 1;
    int half = blockIdx.x & 1;
    if (blockIdx.x == 0) stats[tid] = 0.f;     // 256 entries
    if (half == 0 && tid < 128) Wh[h * 128 + tid] = (_Float16)W[h * 128 + tid];
    if (tid < 32) {
        int n = tid, idx = h * 32 + n;
        float ar = expf(logA[idx]);
        float ai = Aim[idx];
        float dt = expf(logdt[h]);
        float dre = -ar * dt, dim = ai * dt;
        float er = expf(dre);
        float wr = er * cosf(dim), wi = er * sinf(dim);
        WL[n] = (float2){wr, wi};
        if (half == 0) {
            float eL = expf(dre * 256.f);
            Pw[idx]        = eL * cosf(dim * 256.f);
            Pw[4096 + idx] = eL * sinf(dim * 256.f);
        }
        float den  = ar * ar + ai * ai;
        float numr = -(wr - 1.f) * ar + wi * ai;
        float numi = -wi * ar - (wr - 1.f) * ai;
        float Kr = numr / den, Ki = numi / den;
        float c0r = C_re[idx],        c0i = C_im[idx];
        float c1r = C_re[4096 + idx], c1i = C_im[4096 + idx];
        float g0r = 2.f * (c0r * Kr - c0i * Ki), g0i = 2.f * (c0r * Ki + c0i * Kr);
        float g1r = 2.f * (c1r * Kr - c1i * Ki);
        float g1i = 2.f * (c1r * Ki + c1i * Kr);
        G01[n] = (float4){g0r, g0i, g1r, g1i};
        HG[n]  = (float4){g0r * wr - g0i * wi, g0r * wi + g0i * wr, g1r, g1i};
    }
    __syncthreads();
    // ---- build P[n][t]: thread (n = tid&31, tg = tid>>5) owns t = tg + 8j ----
    {
        int n = tid & 31, tg = tid >> 5;
        float2 w = WL[n];
        float w2r = w.x * w.x - w.y * w.y,   w2i = 2.f * w.x * w.y;
        float w4r = w2r * w2r - w2i * w2i,   w4i = 2.f * w2r * w2i;
        float w8r = w4r * w4r - w4i * w4i,   w8i = 2.f * w4r * w4i;
        float pr = (tg & 1) ? w.x : 1.f;
        float pi = (tg & 1) ? w.y : 0.f;
        if (tg & 2) { float t2 = pr * w2r - pi * w2i; pi = pr * w2i + pi * w2r; pr = t2; }
        if (tg & 4) { float t4 = pr * w4r - pi * w4i; pi = pr * w4i + pi * w4r; pr = t4; }
        float2* row = &PL[n * 257];
        #pragma unroll
        for (int j = 0; j < 32; j++) {
            row[tg + 8 * j] = (float2){pr, pi};
            float tr = pr * w8r - pi * w8i; pi = pr * w8i + pi * w8r; pr = tr;
        }
    }
    __syncthreads();
    // ---- k0/k1 ----
    {
        int tau = tid;
        float s0 = 0.f, s1 = 0.f;
        #pragma unroll
        for (int n = 0; n < 32; n++) {
            float2 p = PL[n * 257 + tau];
            float4 g = G01[n];
            s0 += g.x * p.x - g.y * p.y;
            s1 += g.z * p.x - g.w * p.y;
        }
        k0L[tau] = s0; k1L[tau] = s1;
    }
    __syncthreads();
    // ---- KM table (half 0 only): KMrev -> two parity-staggered dword copies ----
    if (half == 0) {
        KMl[tid]       = (_Float16)k0L[255 - tid];
        KMl[256 + tid] = (_Float16)k1L[tid];
        if (tid == 0) { KMl[512] = (_Float16)0.f; KMl[513] = (_Float16)0.f; }
    }
    __syncthreads();
    if (half == 0) {
        union { _Float16 hh[2]; uint u; } pa, pb;
        pa.hh[0] = KMl[2 * tid];     pa.hh[1] = KMl[2 * tid + 1];
        pb.hh[0] = KMl[2 * tid + 1]; pb.hh[1] = KMl[2 * tid + 2];
        kmg[(size_t)h * 512 + tid]       = pa.u;
        kmg[(size_t)h * 512 + 256 + tid] = pb.u;
    }
    // ---- carry-coefficient columns (compact cT, this block's t-half) ----
    #pragma unroll 4
    for (int i = 0; i < 16; i++) {
        int idx = i * 256 + tid;
        int n = idx & 31;
        int t = half * 128 + (idx >> 5);
        float2 pt = PL[n * 257 + t];
        float2 pu = PL[n * 257 + 255 - t];
        float4 hg = HG[n];
        size_t rb = ((size_t)(h * 256 + t)) * 128;
        *(uint*)&cT[rb + 2 * n]      = pk2(hg.x * pt.x - hg.y * pt.y,
                                           -(hg.x * pt.y + hg.y * pt.x));
        *(uint*)&cT[rb + 64 + 2 * n] = pk2(hg.z * pu.x - hg.w * pu.y,
                                           -(hg.z * pu.y + hg.w * pu.x));
    }
    // ---- eT half ----
    #pragma unroll 4
    for (int i = 0; i < 16; i++) {
        int idx = i * 256 + tid;
        int n = idx >> 7;
        int s = half * 128 + (idx & 127);
        float2 ps = PL[n * 257 + s];
        float2 pu = PL[n * 257 + 255 - s];
        size_t base = (size_t)h * 128 * 256;
        eT[base + (size_t)(2 * n) * 256 + s]      = (_Float16)pu.x;
        eT[base + (size_t)(2 * n + 1) * 256 + s]  = (_Float16)pu.y;
        eT[base + (size_t)(64 + 2 * n) * 256 + s] = (_Float16)ps.x;
        eT[base + (size_t)(65 + 2 * n) * 256 + s] = (_Float16)ps.y;
    }
}

// ---------------- K2: chunk-end states GEMM + in-block carry propagation ----------------
// Split by direction d: grid 512 = (h, mt, d), 2 blocks/CU. Depth-2 register prefetch
// with FULLY UNROLLED kt loop (static set indices -> registers, not scratch).
// States parked fp32 in dead At/Bt LDS (stride 66); d==0 blocks also emit xh = (f16)x.
__global__ __launch_bounds__(256, 2) void k_states_c(const float* __restrict__ x,
                                                     const _Float16* __restrict__ eT,
                                                     const float* __restrict__ Pw,
                                                     _Float16* __restrict__ xh,
                                                     _Float16* __restrict__ carr) {
    __shared__ float Sf[128 * 66];                 // 33.8 KB; aliases At/Bt below
    _Float16* SMh = (_Float16*)Sf;
    // At[buf] = SMh + buf*5120   (128 rows x 40 f16)
    // Bt[buf] = SMh + 10240 + buf*2560 (64 rows x 40 f16)
    int tid = threadIdx.x;
    // XCD swizzle: 4 blocks of same h (mt x d) on one XCD for eT L2 reuse (512 = 64*8)
    int xcd = blockIdx.x & 7, slot = blockIdx.x >> 3;
    int h = xcd * 16 + (slot >> 2);
    int mt = (slot >> 1) & 1, d = slot & 1;
    int wave = tid >> 6, lane = tid & 63;
    int wm = wave >> 1, wn = wave & 1;
    int lrow = lane & 15, quad = lane >> 4;
    int koff = quad * 8;
    f32x4 acc[4][2];
    #pragma unroll
    for (int a = 0; a < 4; a++)
        #pragma unroll
        for (int b = 0; b < 2; b++) acc[a][b] = (f32x4){0.f, 0.f, 0.f, 0.f};

    const int chA = tid >> 3, segA = tid & 7;
    const size_t xbase = (((size_t)(mt * 4) * HCH + h) << 13) + (chA << 8) + segA * 4;
    const int rB = tid >> 2, sgB = tid & 3;

    float4 ar[2][4]; uint4 br[2];   // depth-2 register sets (all indices compile-time)
    #define LOADA_S(s, kk) { _Pragma("unroll") for (int i = 0; i < 4; i++) \
        ar[s][i] = *(const float4*)(x + xbase + ((size_t)i << 20) + (kk)); }
    #define LOADB_S(s, kk) { br[s] = *(const uint4*)(eT + ((size_t)(h * 128 + d * 64 + rB)) * 256 + (kk) + sgB * 8); }
    #define WRITE_S(s, buf, kk) { _Pragma("unroll") for (int i = 0; i < 4; i++) { \
            uint2 o; o.x = pk2(ar[s][i].x, ar[s][i].y); o.y = pk2(ar[s][i].z, ar[s][i].w); \
            *(uint2*)&SMh[(buf) * 5120 + (chA + 32 * i) * 40 + segA * 4] = o; \
            if (d == 0) *(uint2*)&xh[xbase + ((size_t)i << 20) + (kk)] = o; } \
        *(uint4*)&SMh[10240 + (buf) * 2560 + rB * 40 + sgB * 8] = br[s]; }

    LOADA_S(0, 0);  LOADB_S(0, 0);
    LOADA_S(1, 32); LOADB_S(1, 32);
    WRITE_S(0, 0, 0);
    __syncthreads();
    #pragma unroll
    for (int kt = 0; kt < 8; kt++) {
        const int cur = kt & 1;
        if (kt < 6) { LOADA_S(kt & 1, (kt + 2) * 32); LOADB_S(kt & 1, (kt + 2) * 32); }
        f16x8 a[4], b[2];
        #pragma unroll
        for (int f = 0; f < 4; f++)
            a[f] = *(const f16x8*)&SMh[cur * 5120 + (wm * 64 + f * 16 + lrow) * 40 + koff];
        #pragma unroll
        for (int f = 0; f < 2; f++)
            b[f] = *(const f16x8*)&SMh[10240 + cur * 2560 + (wn * 32 + f * 16 + lrow) * 40 + koff];
        #pragma unroll
        for (int fi = 0; fi < 4; fi++)
            #pragma unroll
            for (int fj = 0; fj < 2; fj++)
                acc[fi][fj] = __builtin_amdgcn_mfma_f32_16x16x32_f16(a[fi], b[fj], acc[fi][fj], 0, 0, 0);
        if (kt < 7) {
            WRITE_S((kt + 1) & 1, cur ^ 1, (kt + 1) * 32);
            __syncthreads();
        }
    }
    __syncthreads();   // At/Bt dead; repurpose as fp32 S park (stride 66)
    #pragma unroll
    for (int fi = 0; fi < 4; fi++) {
        #pragma unroll
        for (int fj = 0; fj < 2; fj++) {
            int srow = wn * 32 + fj * 16 + lrow;   // local srow within this d
            #pragma unroll
            for (int rg = 0; rg < 4; rg++) {
                int bc = wm * 64 + fi * 16 + quad * 4 + rg;
                Sf[bc * 66 + srow] = acc[fi][fj][rg];
            }
        }
    }
    __syncthreads();
    if (tid < 128) {     // 128 chains: 4 blocs x 32 n, direction d
        int bloc = tid >> 5, n = tid & 31;
        float wLr = Pw[h * 32 + n], wLi = Pw[4096 + h * 32 + n];
        float cr = 0.f, ci = 0.f;
        size_t gb = ((size_t)(h * 256 + mt * 128 + bloc * 32)) * 128 + d * 64 + 2 * n;
        if (d == 0) {
            for (int c = 0; c < CCH; c++) {
                *(uint*)&carr[gb + (size_t)c * 128] = pk2(cr, ci);
                float2 s = *(const float2*)&Sf[(bloc * 32 + c) * 66 + 2 * n];
                float nr = fmaf(wLr, cr, -wLi * ci) + s.x;
                float ni = fmaf(wLi, cr,  wLr * ci) + s.y;
                cr = nr; ci = ni;
            }
        } else {
            for (int c = CCH - 1; c >= 0; c--) {
                *(uint*)&carr[gb + (size_t)c * 128] = pk2(cr, ci);
                float2 s = *(const float2*)&Sf[(bloc * 32 + c) * 66 + 2 * n];
                float nr = fmaf(wLr, cr, -wLi * ci) + s.x;
                float ni = fmaf(wLi, cr,  wLr * ci) + s.y;
                cr = nr; ci = ni;
            }
        }
    }
    #undef LOADA_S
    #undef LOADB_S
    #undef WRITE_S
}

// ---------------- K3: bidirectional conv GEMM + fused skip+GELU -> f16 Yg ----------------
// N=64 t-tile, grid 1024 -> 4 blocks/CU. Depth-2 register prefetch on A with FULLY
// UNROLLED kt loop (static set indices). Toeplitz K-steps (kt<8): B gathered from the
// 2 KB KM LDS table. Carry K-steps (kt>=8): B read from Bc (XOR-swizzled cT preload).
__global__ __launch_bounds__(256, 4) void k_conv_g(const _Float16* __restrict__ xh,
                                                   const uint* __restrict__ kmg,
                                                   const _Float16* __restrict__ cT,
                                                   const _Float16* __restrict__ carr,
                                                   const float* __restrict__ D,
                                                   _Float16* __restrict__ Yg) {
    __shared__ _Float16 At[2][128 * 40];   // 20480 B
    __shared__ _Float16 Bc[64 * 128];      // 16384 B, XOR-swizzled (col ^ ((row&7)<<3))
    __shared__ uint KMA[256], KMB[256];    // 2048 B   -> total 38912 B, 4 blocks/CU
    int tid = threadIdx.x;
    // XCD swizzle: 8 blocks sharing h (2 mt x 4 nt) on one XCD (1024 = 128*8)
    int xcd = blockIdx.x & 7, slot = blockIdx.x >> 3;   // slot in [0,128)
    int h   = xcd * 16 + (slot >> 3);
    int sub = slot & 7;
    int mt = sub >> 2, nt = sub & 3;        // nt in [0,4): 64-wide t-tile
    int wave = tid >> 6, lane = tid & 63;
    int wm = wave >> 1, wn = wave & 1;
    int lrow = lane & 15, quad = lane >> 4;
    int koff = quad * 8;
    f32x4 acc[4][2];
    #pragma unroll
    for (int a = 0; a < 4; a++)
        #pragma unroll
        for (int b = 0; b < 2; b++) acc[a][b] = (f32x4){0.f, 0.f, 0.f, 0.f};

    const int rS = tid >> 2, sgS = tid & 3;

    uint4 a_r[2][2];   // depth-2 register sets (static indices only)
    #define LOADA_C(s, kk) { _Pragma("unroll") for (int i = 0; i < 2; i++) { \
            int bc = mt * 128 + rS + 64 * i; \
            a_r[s][i] = ((kk) < 256) \
              ? *(const uint4*)(xh + (((size_t)((bc >> 5) * HCH + h)) << 13) + ((bc & 31) << 8) + (kk) + sgS * 8) \
              : *(const uint4*)(carr + ((size_t)(h * 256 + bc)) * 128 + ((kk) - 256) + sgS * 8); } }
    #define WRITE_A(s, buf) { _Pragma("unroll") for (int i = 0; i < 2; i++) \
        *(uint4*)&At[buf][(rS + 64 * i) * 40 + sgS * 8] = a_r[s][i]; }

    LOADA_C(0, 0);
    LOADA_C(1, 32);
    // one-shot preloads: KM table, Bc panel (64 t-rows x 128 carry cols, swizzled)
    KMA[tid] = kmg[(size_t)h * 512 + tid];
    KMB[tid] = kmg[(size_t)h * 512 + 256 + tid];
    #pragma unroll
    for (int i = 0; i < 4; i++) {
        int idx = tid + i * 256;            // [0,1024)
        int r = idx >> 4, sg = idx & 15;    // r in [0,64), col granule sg*8
        uint4 v = *(const uint4*)(cT + ((size_t)(h * 256 + nt * 64 + r)) * 128 + sg * 8);
        *(uint4*)&Bc[r * 128 + ((sg * 8) ^ ((r & 7) << 3))] = v;
    }
    WRITE_A(0, 0);
    __syncthreads();
    #pragma unroll
    for (int kt = 0; kt < 12; kt++) {
        const int cur = kt & 1;
        if (kt < 10) LOADA_C(kt & 1, (kt + 2) * 32);
        f16x8 a[4], b[2];
        #pragma unroll
        for (int f = 0; f < 4; f++)
            a[f] = *(const f16x8*)&At[cur][(wm * 64 + f * 16 + lrow) * 40 + koff];
        if (kt < 8) {
            int kk = kt * 32;
            #pragma unroll
            for (int f = 0; f < 2; f++) {
                int t_f = nt * 64 + wn * 32 + f * 16 + lrow;
                int idx0 = 255 - t_f + kk + koff;
                int par = idx0 & 1;
                int dw = idx0 >> 1;
                const uint* kp = par ? KMB : KMA;
                union { uint u[4]; f16x8 v; } bu;
                bu.u[0] = kp[dw]; bu.u[1] = kp[dw + 1]; bu.u[2] = kp[dw + 2]; bu.u[3] = kp[dw + 3];
                b[f] = bu.v;
            }
        } else {
            int cb = kt * 32 - 256 + koff;
            #pragma unroll
            for (int f = 0; f < 2; f++) {
                int r2 = wn * 32 + f * 16 + lrow;
                b[f] = *(const f16x8*)&Bc[r2 * 128 + (cb ^ ((r2 & 7) << 3))];
            }
        }
        #pragma unroll
        for (int fi = 0; fi < 4; fi++)
            #pragma unroll
            for (int fj = 0; fj < 2; fj++)
                acc[fi][fj] = __builtin_amdgcn_mfma_f32_16x16x32_f16(a[fi], b[fj], acc[fi][fj], 0, 0, 0);
        if (kt < 11) {
            WRITE_A((kt + 1) & 1, cur ^ 1);
            __syncthreads();
        }
    }
    // fused epilogue: skip + GELU -> f16 store (xh is L2-hot from A-staging)
    float Dh = D[h];
    #pragma unroll
    for (int fi = 0; fi < 4; fi++) {
        #pragma unroll
        for (int fj = 0; fj < 2; fj++) {
            int t = nt * 64 + wn * 32 + fj * 16 + lrow;
            #pragma unroll
            for (int rg = 0; rg < 4; rg++) {
                int bc = mt * 128 + wm * 64 + fi * 16 + quad * 4 + rg;
                size_t base = (((size_t)((bc >> 5) * HCH + h)) << 13) + ((bc & 31) << 8) + t;
                float xv = (float)xh[base];
                float yv = acc[fi][fj][rg] + Dh * xv;
                Yg[base] = (_Float16)gelu_f(yv);
            }
        }
    }
    #undef LOADA_C
    #undef WRITE_A
}

// ---------------- K4: pointwise conv GEMM + BN stats ----------------
// Full-panel preload: the block's entire 128x128 Yg tile is loaded in ONE burst
// (8 uint4/thread, static indices) into a single 34 KB LDS buffer -> one latency
// exposure, then 4 pure-LDS MFMA steps with zero mid-loop global traffic.
__global__ __launch_bounds__(256, 2) void k_pointwise(const _Float16* __restrict__ Yg,
                                                      const _Float16* __restrict__ Wh,
                                                      _Float16* __restrict__ z,
                                                      float* __restrict__ stats) {
    __shared__ _Float16 Yt[128 * 136];     // 34816 B, transposed [l][h], pad 136
    __shared__ float Ls[512];
    int tid = threadIdx.x;
    int b  = blockIdx.x >> 6;
    int l0 = (blockIdx.x & 63) << 7;
    int wave = tid >> 6, lane = tid & 63;
    int wm = wave >> 1, wn = wave & 1;
    int lrow = lane & 15, quad = lane >> 4;
    int koff = quad * 8;
    f32x4 acc[4][4];
    #pragma unroll
    for (int a = 0; a < 4; a++)
        #pragma unroll
        for (int c = 0; c < 4; c++) acc[a][c] = (f32x4){0.f, 0.f, 0.f, 0.f};

    // issue the full Y panel load burst first (16 threads per h-row, 256 B each)
    uint4 yv[8];
    #pragma unroll
    for (int i = 0; i < 8; i++) {
        int g = i * 256 + tid;
        int hh = g >> 4, lg = g & 15;
        yv[i] = *(const uint4*)(Yg + (((size_t)(b * HCH + hh)) << 13) + l0 + lg * 8);
    }
    // W fragments from L2-resident Wh while Y loads are in flight
    f16x8 a[4][4];
    #pragma unroll
    for (int ks = 0; ks < 4; ks++)
        #pragma unroll
        for (int f = 0; f < 4; f++)
            a[ks][f] = *(const f16x8*)(Wh + (wm * 64 + f * 16 + lrow) * HCH + ks * 32 + koff);
    // transpose-write panel to LDS
    #pragma unroll
    for (int i = 0; i < 8; i++) {
        int g = i * 256 + tid;
        int hh = g >> 4, lg = g & 15;
        const _Float16* hv = (const _Float16*)&yv[i];
        #pragma unroll
        for (int j = 0; j < 8; j++)
            Yt[(lg * 8 + j) * 136 + hh] = hv[j];
    }
    __syncthreads();
    #pragma unroll
    for (int kt = 0; kt < 4; kt++) {
        f16x8 bf[4];
        #pragma unroll
        for (int f = 0; f < 4; f++)
            bf[f] = *(const f16x8*)&Yt[(wn * 64 + f * 16 + lrow) * 136 + kt * 32 + koff];
        #pragma unroll
        for (int fi = 0; fi < 4; fi++)
            #pragma unroll
            for (int fj = 0; fj < 4; fj++)
                acc[fi][fj] = __builtin_amdgcn_mfma_f32_16x16x32_f16(a[kt][fi], bf[fj], acc[fi][fj], 0, 0, 0);
    }
    // store z (f16)
    #pragma unroll
    for (int fi = 0; fi < 4; fi++) {
        #pragma unroll
        for (int fj = 0; fj < 4; fj++) {
            int l = l0 + wn * 64 + fj * 16 + lrow;
            #pragma unroll
            for (int rg = 0; rg < 4; rg++) {
                int o = wm * 64 + fi * 16 + quad * 4 + rg;
                z[(((size_t)(b * HCH + o)) << 13) + l] = (_Float16)acc[fi][fj][rg];
            }
        }
    }
    // fused BN stats: 16-lane DPP butterfly, LDS, atomics (fire-and-forget)
    #pragma unroll
    for (int fi = 0; fi < 4; fi++) {
        #pragma unroll
        for (int rg = 0; rg < 4; rg++) {
            float s = 0.f, q = 0.f;
            #pragma unroll
            for (int fj = 0; fj < 4; fj++) {
                float v = acc[fi][fj][rg];
                s += v; q = fmaf(v, v, q);
            }
            DPP_ADD(s, 0xB1); DPP_ADD(s, 0x4E); DPP_ADD(s, 0x141); DPP_ADD(s, 0x140);
            DPP_ADD(q, 0xB1); DPP_ADD(q, 0x4E); DPP_ADD(q, 0x141); DPP_ADD(q, 0x140);
            if (lrow == 0) {
                int olo = fi * 16 + quad * 4 + rg;
                Ls[wave * 64 + olo]       = s;
                Ls[256 + wave * 64 + olo] = q;
            }
        }
    }
    __syncthreads();
    if (tid < HCH) {
        int wmn = tid >> 6;
        int olo = tid & 63;
        float s = Ls[(wmn * 2) * 64 + olo] + Ls[(wmn * 2 + 1) * 64 + olo];
        float q = Ls[256 + (wmn * 2) * 64 + olo] + Ls[256 + (wmn * 2 + 1) * 64 + olo];
        atomicAdd(&stats[tid], s);
        atomicAdd(&stats[HCH + tid], q);
    }
}

// ---------------- K5: BN normalize + ELU + residual (z f16, residual from xh f16) ----
__global__ __launch_bounds__(256) void k_final(const _Float16* __restrict__ z,
                                               const _Float16* __restrict__ xh,
                                               const float* __restrict__ stats,
                                               const float* __restrict__ gamma,
                                               const float* __restrict__ beta,
                                               float* __restrict__ out) {
    size_t i8 = (size_t)blockIdx.x * 256 + threadIdx.x;   // 1,048,576 total, 8 elems each
    int o = (int)((i8 >> 10) & (HCH - 1));
    const float inv_cnt = 1.f / (float)(BB * LLEN);
    float m   = stats[o] * inv_cnt;
    float var = stats[HCH + o] * inv_cnt - m * m;
    float rs  = rsqrtf(var + 1e-5f);
    float ga  = gamma[o] * rs;
    float bt  = beta[o] - m * ga;
    uint4 zv = ((const uint4*)z)[i8];
    uint4 xv = ((const uint4*)xh)[i8];
    const _Float16* zh = (const _Float16*)&zv;
    const _Float16* xf = (const _Float16*)&xv;
    float4 ra, rb;
    { float t = fmaf((float)zh[0], ga, bt); float e = t > 0.f ? t : (__expf(t) - 1.f); ra.x = e + (float)xf[0]; }
    { float t = fmaf((float)zh[1], ga, bt); float e = t > 0.f ? t : (__expf(t) - 1.f); ra.y = e + (float)xf[1]; }
    { float t = fmaf((float)zh[2], ga, bt); float e = t > 0.f ? t : (__expf(t) - 1.f); ra.z = e + (float)xf[2]; }
    { float t = fmaf((float)zh[3], ga, bt); float e = t > 0.f ? t : (__expf(t) - 1.f); ra.w = e + (float)xf[3]; }
    { float t = fmaf((float)zh[4], ga, bt); float e = t > 0.f ? t : (__expf(t) - 1.f); rb.x = e + (float)xf[4]; }
    { float t = fmaf((float)zh[5], ga, bt); float e = t > 0.f ? t : (__expf(t) - 1.f); rb.y = e + (float)xf[5]; }
    { float t = fmaf((float)zh[6], ga, bt); float e = t > 0.f ? t : (__expf(t) - 1.f); rb.z = e + (float)xf[6]; }
    { float t = fmaf((float)zh[7], ga, bt); float e = t > 0.f ? t : (__expf(t) - 1.f); rb.w = e + (float)xf[7]; }
    ((float4*)out)[2 * i8]     = ra;
    ((float4*)out)[2 * i8 + 1] = rb;
}

extern "C" void kernel_launch(void* const* d_in, const int* in_sizes, int n_in,
                              void* d_out, int out_size, void* d_ws, size_t ws_size,
                              hipStream_t stream) {
    const float* x     = (const float*)d_in[0];
    const float* C_re  = (const float*)d_in[1];
    const float* C_im  = (const float*)d_in[2];
    const float* logA  = (const float*)d_in[3];
    const float* Aim   = (const float*)d_in[4];
    const float* logdt = (const float*)d_in[5];
    const float* D     = (const float*)d_in[6];
    const float* W     = (const float*)d_in[7];
    const float* gamma = (const float*)d_in[8];
    const float* beta  = (const float*)d_in[9];

    float* ws = (float*)d_ws;
    // [0 .. 2097152): eT f16 (dead after k_states_c)
    // [0 .. 4194304): Yg f16 (written by k_conv_g, after eT dead)
    _Float16* eT    = (_Float16*)ws;
    _Float16* Yg    = (_Float16*)ws;
    // [8388608 .. 12582912): zf f16
    _Float16* zf    = (_Float16*)(ws + 8388608);
    // [12582912 .. 14680064): cT f16 (carry-coefficient columns, compact)
    _Float16* cT    = (_Float16*)(ws + 12582912);
    // [14680064 .. 14745600): kmg (128 h x 512 uints)
    uint*     kmg   = (uint*)(ws + 14680064);
    // [16777216 ..): carr f16, Pw, stats, Wh f16, xh f16
    _Float16* carr  = (_Float16*)(ws + 16777216);
    float*    Pw    = ws + 16777216 + 2097152;           // 18874368
    float*    stats = Pw + 8192;                          // 18882560 (256 floats)
    _Float16* Wh    = (_Float16*)(ws + 18882880);         // 16384 f16
    _Float16* xh    = (_Float16*)(ws + 18891072);         // 8.39M f16
    float*    out   = (float*)d_out;

    k_prep     <<<256,  256, 0, stream>>>(C_re, C_im, logA, Aim, logdt, W, cT, kmg, eT, Wh, Pw, stats);
    k_states_c <<<512,  256, 0, stream>>>(x, eT, Pw, xh, carr);
    k_conv_g   <<<1024, 256, 0, stream>>>(xh, kmg, cT, carr, D, Yg);
    k_pointwise<<<512,  256, 0, stream>>>(Yg, Wh, zf, stats);
    k_final    <<<4096, 256, 0, stream>>>(zf, xh, stats, gamma, beta, out);
}

// Round 13
// 173.226 us; speedup vs baseline: 1.2379x; 1.2379x over previous
//
#include <hip/hip_runtime.h>
#include <math.h>

#define HCH   128
#define NMODE 32
#define BB    8
#define LLEN  8192
#define LC    256
#define CCH   (LLEN / LC)      // 32 chunks per row
#define ROWS  (BB * HCH)       // 1024

typedef unsigned int uint;
typedef _Float16 f16x8 __attribute__((ext_vector_type(8)));
typedef float    f32x4 __attribute__((ext_vector_type(4)));

static __device__ __forceinline__ uint pk2(float a, float b) {
    union { _Float16 h[2]; uint u; } v;
    v.h[0] = (_Float16)a; v.h[1] = (_Float16)b;
    return v.u;
}

// branch-free GELU via A&S 7.1.25 erf approx (|err| <= 5e-4)
__device__ __forceinline__ float gelu_f(float y) {
    float z = fabsf(y) * 0.7071067811865476f;
    float p = fmaf(z, 0.078108f, 0.000972f);
    p = fmaf(z, p, 0.230389f);
    p = fmaf(z, p, 0.278393f);
    p = fmaf(z, p, 1.0f);
    float p2 = p * p;
    float p4 = p2 * p2;
    float er = 1.f - __builtin_amdgcn_rcpf(p4);
    float s  = copysignf(er, y);
    return 0.5f * y * (1.f + s);
}

// VALU-pipe cross-lane add (DPP)
#define DPP_ADD(v, ctrl) { int _t = __builtin_amdgcn_update_dpp(0, __float_as_int(v), \
                             (ctrl), 0xF, 0xF, true); (v) += __int_as_float(_t); }

// ---------------- K1: per-h params -> KM table + carry cols (cT) + eT + Wh ----------------
// 256 blocks (2 per h). P[n][t]=w_n^t built in LDS (w^8 recurrence).
// KMrev[i] = km[255-i]; packed as two parity-staggered dword copies so any 2B-aligned
// 8xf16 run is 4 aligned dword reads. Toeplitz block is NEVER materialized.
__global__ __launch_bounds__(256) void k_prep(const float* __restrict__ C_re,
                                              const float* __restrict__ C_im,
                                              const float* __restrict__ logA,
                                              const float* __restrict__ Aim,
                                              const float* __restrict__ logdt,
                                              const float* __restrict__ W,
                                              _Float16* __restrict__ cT,
                                              uint* __restrict__ kmg,
                                              _Float16* __restrict__ eT,
                                              _Float16* __restrict__ Wh,
                                              float* __restrict__ Pw,
                                              float* __restrict__ stats) {
    __shared__ float2 PL[32 * 257];   // P[n][t], row stride 257 (bank-spread)
    __shared__ float4 G01[32];        // (G0r, G0i, G1r, G1i)
    __shared__ float4 HG[32];         // (H0r, H0i, G1r, G1i)
    __shared__ float2 WL[32];         // (wr, wi)
    __shared__ float k0L[256], k1L[256];
    __shared__ _Float16 KMl[516];
    int tid  = threadIdx.x;
    int h    = blockIdx.x >> 1;
    int half = blockIdx.x & 1;
    if (blockIdx.x == 0) stats[tid] = 0.f;     // 256 entries
    if (half == 0 && tid < 128) Wh[h * 128 + tid] = (_Float16)W[h * 128 + tid];
    if (tid < 32) {
        int n = tid, idx = h * 32 + n;
        float ar = expf(logA[idx]);
        float ai = Aim[idx];
        float dt = expf(logdt[h]);
        float dre = -ar * dt, dim = ai * dt;
        float er = expf(dre);
        float wr = er * cosf(dim), wi = er * sinf(dim);
        WL[n] = (float2){wr, wi};
        if (half == 0) {
            float eL = expf(dre * 256.f);
            Pw[idx]        = eL * cosf(dim * 256.f);
            Pw[4096 + idx] = eL * sinf(dim * 256.f);
        }
        float den  = ar * ar + ai * ai;
        float numr = -(wr - 1.f) * ar + wi * ai;
        float numi = -wi * ar - (wr - 1.f) * ai;
        float Kr = numr / den, Ki = numi / den;
        float c0r = C_re[idx],        c0i = C_im[idx];
        float c1r = C_re[4096 + idx], c1i = C_im[4096 + idx];
        float g0r = 2.f * (c0r * Kr - c0i * Ki), g0i = 2.f * (c0r * Ki + c0i * Kr);
        float g1r = 2.f * (c1r * Kr - c1i * Ki);
        float g1i = 2.f * (c1r * Ki + c1i * Kr);
        G01[n] = (float4){g0r, g0i, g1r, g1i};
        HG[n]  = (float4){g0r * wr - g0i * wi, g0r * wi + g0i * wr, g1r, g1i};
    }
    __syncthreads();
    // ---- build P[n][t]: thread (n = tid&31, tg = tid>>5) owns t = tg + 8j ----
    {
        int n = tid & 31, tg = tid >> 5;
        float2 w = WL[n];
        float w2r = w.x * w.x - w.y * w.y,   w2i = 2.f * w.x * w.y;
        float w4r = w2r * w2r - w2i * w2i,   w4i = 2.f * w2r * w2i;
        float w8r = w4r * w4r - w4i * w4i,   w8i = 2.f * w4r * w4i;
        float pr = (tg & 1) ? w.x : 1.f;
        float pi = (tg & 1) ? w.y : 0.f;
        if (tg & 2) { float t2 = pr * w2r - pi * w2i; pi = pr * w2i + pi * w2r; pr = t2; }
        if (tg & 4) { float t4 = pr * w4r - pi * w4i; pi = pr * w4i + pi * w4r; pr = t4; }
        float2* row = &PL[n * 257];
        #pragma unroll
        for (int j = 0; j < 32; j++) {
            row[tg + 8 * j] = (float2){pr, pi};
            float tr = pr * w8r - pi * w8i; pi = pr * w8i + pi * w8r; pr = tr;
        }
    }
    __syncthreads();
    // ---- k0/k1 ----
    {
        int tau = tid;
        float s0 = 0.f, s1 = 0.f;
        #pragma unroll
        for (int n = 0; n < 32; n++) {
            float2 p = PL[n * 257 + tau];
            float4 g = G01[n];
            s0 += g.x * p.x - g.y * p.y;
            s1 += g.z * p.x - g.w * p.y;
        }
        k0L[tau] = s0; k1L[tau] = s1;
    }
    __syncthreads();
    // ---- KM table (half 0 only): KMrev -> two parity-staggered dword copies ----
    if (half == 0) {
        KMl[tid]       = (_Float16)k0L[255 - tid];
        KMl[256 + tid] = (_Float16)k1L[tid];
        if (tid == 0) { KMl[512] = (_Float16)0.f; KMl[513] = (_Float16)0.f; }
    }
    __syncthreads();
    if (half == 0) {
        union { _Float16 hh[2]; uint u; } pa, pb;
        pa.hh[0] = KMl[2 * tid];     pa.hh[1] = KMl[2 * tid + 1];
        pb.hh[0] = KMl[2 * tid + 1]; pb.hh[1] = KMl[2 * tid + 2];
        kmg[(size_t)h * 512 + tid]       = pa.u;
        kmg[(size_t)h * 512 + 256 + tid] = pb.u;
    }
    // ---- carry-coefficient columns (compact cT, this block's t-half) ----
    #pragma unroll 4
    for (int i = 0; i < 16; i++) {
        int idx = i * 256 + tid;
        int n = idx & 31;
        int t = half * 128 + (idx >> 5);
        float2 pt = PL[n * 257 + t];
        float2 pu = PL[n * 257 + 255 - t];
        float4 hg = HG[n];
        size_t rb = ((size_t)(h * 256 + t)) * 128;
        *(uint*)&cT[rb + 2 * n]      = pk2(hg.x * pt.x - hg.y * pt.y,
                                           -(hg.x * pt.y + hg.y * pt.x));
        *(uint*)&cT[rb + 64 + 2 * n] = pk2(hg.z * pu.x - hg.w * pu.y,
                                           -(hg.z * pu.y + hg.w * pu.x));
    }
    // ---- eT half ----
    #pragma unroll 4
    for (int i = 0; i < 16; i++) {
        int idx = i * 256 + tid;
        int n = idx >> 7;
        int s = half * 128 + (idx & 127);
        float2 ps = PL[n * 257 + s];
        float2 pu = PL[n * 257 + 255 - s];
        size_t base = (size_t)h * 128 * 256;
        eT[base + (size_t)(2 * n) * 256 + s]      = (_Float16)pu.x;
        eT[base + (size_t)(2 * n + 1) * 256 + s]  = (_Float16)pu.y;
        eT[base + (size_t)(64 + 2 * n) * 256 + s] = (_Float16)ps.x;
        eT[base + (size_t)(65 + 2 * n) * 256 + s] = (_Float16)ps.y;
    }
}

// ---------------- K2: chunk-end states GEMM + in-block carry propagation ----------------
// Split by direction d: grid 512 = (h, mt, d), N=64 srows per block -> 2 blocks/CU.
// States parked fp32 in dead At/Bt LDS (stride 66), chains from LDS.
// d==0 blocks also emit xh = (f16)x.
__global__ __launch_bounds__(256, 2) void k_states_c(const float* __restrict__ x,
                                                     const _Float16* __restrict__ eT,
                                                     const float* __restrict__ Pw,
                                                     _Float16* __restrict__ xh,
                                                     _Float16* __restrict__ carr) {
    __shared__ float Sf[128 * 66];                 // 33.8 KB; aliases At/Bt below
    _Float16* SMh = (_Float16*)Sf;
    // At[buf] = SMh + buf*5120   (128 rows x 40 f16)
    // Bt[buf] = SMh + 10240 + buf*2560 (64 rows x 40 f16)
    int tid = threadIdx.x;
    // XCD swizzle: 4 blocks of same h (mt x d) on one XCD for eT L2 reuse (512 = 64*8)
    int xcd = blockIdx.x & 7, slot = blockIdx.x >> 3;
    int h = xcd * 16 + (slot >> 2);
    int mt = (slot >> 1) & 1, d = slot & 1;
    int wave = tid >> 6, lane = tid & 63;
    int wm = wave >> 1, wn = wave & 1;
    int lrow = lane & 15, quad = lane >> 4;
    int koff = quad * 8;
    f32x4 acc[4][2];
    #pragma unroll
    for (int a = 0; a < 4; a++)
        #pragma unroll
        for (int b = 0; b < 2; b++) acc[a][b] = (f32x4){0.f, 0.f, 0.f, 0.f};

    const int chA = tid >> 3, segA = tid & 7;
    const size_t xbase = (((size_t)(mt * 4) * HCH + h) << 13) + (chA << 8) + segA * 4;
    const int rB = tid >> 2, sgB = tid & 3;

    float4 ar[4]; uint4 br;
    #define LOADA_S(kk) { _Pragma("unroll") for (int i = 0; i < 4; i++) \
        ar[i] = *(const float4*)(x + xbase + ((size_t)i << 20) + (kk)); }
    #define LOADB_S(kk) { br = *(const uint4*)(eT + ((size_t)(h * 128 + d * 64 + rB)) * 256 + (kk) + sgB * 8); }
    #define WRITE_S(buf, kk) { _Pragma("unroll") for (int i = 0; i < 4; i++) { \
            uint2 o; o.x = pk2(ar[i].x, ar[i].y); o.y = pk2(ar[i].z, ar[i].w); \
            *(uint2*)&SMh[(buf) * 5120 + (chA + 32 * i) * 40 + segA * 4] = o; \
            if (d == 0) *(uint2*)&xh[xbase + ((size_t)i << 20) + (kk)] = o; } \
        *(uint4*)&SMh[10240 + (buf) * 2560 + rB * 40 + sgB * 8] = br; }

    LOADA_S(0); LOADB_S(0);
    WRITE_S(0, 0);
    __syncthreads();
    for (int kt = 0; kt < 8; kt++) {
        int cur = kt & 1;
        if (kt < 7) { LOADA_S((kt + 1) * 32); LOADB_S((kt + 1) * 32); }
        f16x8 a[4], b[2];
        #pragma unroll
        for (int f = 0; f < 4; f++)
            a[f] = *(const f16x8*)&SMh[cur * 5120 + (wm * 64 + f * 16 + lrow) * 40 + koff];
        #pragma unroll
        for (int f = 0; f < 2; f++)
            b[f] = *(const f16x8*)&SMh[10240 + cur * 2560 + (wn * 32 + f * 16 + lrow) * 40 + koff];
        #pragma unroll
        for (int fi = 0; fi < 4; fi++)
            #pragma unroll
            for (int fj = 0; fj < 2; fj++)
                acc[fi][fj] = __builtin_amdgcn_mfma_f32_16x16x32_f16(a[fi], b[fj], acc[fi][fj], 0, 0, 0);
        if (kt < 7) {
            WRITE_S(cur ^ 1, (kt + 1) * 32);
            __syncthreads();
        }
    }
    __syncthreads();   // At/Bt dead; repurpose as fp32 S park (stride 66)
    #pragma unroll
    for (int fi = 0; fi < 4; fi++) {
        #pragma unroll
        for (int fj = 0; fj < 2; fj++) {
            int srow = wn * 32 + fj * 16 + lrow;   // local srow within this d
            #pragma unroll
            for (int rg = 0; rg < 4; rg++) {
                int bc = wm * 64 + fi * 16 + quad * 4 + rg;
                Sf[bc * 66 + srow] = acc[fi][fj][rg];
            }
        }
    }
    __syncthreads();
    if (tid < 128) {     // 128 chains: 4 blocs x 32 n, direction d
        int bloc = tid >> 5, n = tid & 31;
        float wLr = Pw[h * 32 + n], wLi = Pw[4096 + h * 32 + n];
        float cr = 0.f, ci = 0.f;
        size_t gb = ((size_t)(h * 256 + mt * 128 + bloc * 32)) * 128 + d * 64 + 2 * n;
        if (d == 0) {
            for (int c = 0; c < CCH; c++) {
                *(uint*)&carr[gb + (size_t)c * 128] = pk2(cr, ci);
                float2 s = *(const float2*)&Sf[(bloc * 32 + c) * 66 + 2 * n];
                float nr = fmaf(wLr, cr, -wLi * ci) + s.x;
                float ni = fmaf(wLi, cr,  wLr * ci) + s.y;
                cr = nr; ci = ni;
            }
        } else {
            for (int c = CCH - 1; c >= 0; c--) {
                *(uint*)&carr[gb + (size_t)c * 128] = pk2(cr, ci);
                float2 s = *(const float2*)&Sf[(bloc * 32 + c) * 66 + 2 * n];
                float nr = fmaf(wLr, cr, -wLi * ci) + s.x;
                float ni = fmaf(wLi, cr,  wLr * ci) + s.y;
                cr = nr; ci = ni;
            }
        }
    }
    #undef LOADA_S
    #undef LOADB_S
    #undef WRITE_S
}

// ---------------- K3: bidirectional conv GEMM + fused skip+GELU -> f16 Yg ----------------
// N=64 t-tile, grid 1024 -> 4 blocks/CU. Toeplitz K-steps (kt<8): B gathered from the
// 2 KB KM LDS table. Carry K-steps (kt>=8): B read from Bc (one-shot XOR-swizzled cT
// preload). Main loop stages only A (double-buffered).
__global__ __launch_bounds__(256, 4) void k_conv_g(const _Float16* __restrict__ xh,
                                                   const uint* __restrict__ kmg,
                                                   const _Float16* __restrict__ cT,
                                                   const _Float16* __restrict__ carr,
                                                   const float* __restrict__ D,
                                                   _Float16* __restrict__ Yg) {
    __shared__ _Float16 At[2][128 * 40];   // 20480 B
    __shared__ _Float16 Bc[64 * 128];      // 16384 B, XOR-swizzled (col ^ ((row&7)<<3))
    __shared__ uint KMA[256], KMB[256];    // 2048 B   -> total 38912 B, 4 blocks/CU
    int tid = threadIdx.x;
    // XCD swizzle: 8 blocks sharing h (2 mt x 4 nt) on one XCD (1024 = 128*8)
    int xcd = blockIdx.x & 7, slot = blockIdx.x >> 3;   // slot in [0,128)
    int h   = xcd * 16 + (slot >> 3);
    int sub = slot & 7;
    int mt = sub >> 2, nt = sub & 3;        // nt in [0,4): 64-wide t-tile
    int wave = tid >> 6, lane = tid & 63;
    int wm = wave >> 1, wn = wave & 1;
    int lrow = lane & 15, quad = lane >> 4;
    int koff = quad * 8;
    f32x4 acc[4][2];
    #pragma unroll
    for (int a = 0; a < 4; a++)
        #pragma unroll
        for (int b = 0; b < 2; b++) acc[a][b] = (f32x4){0.f, 0.f, 0.f, 0.f};

    const int rS = tid >> 2, sgS = tid & 3;

    uint4 a_r[2];
    #define LOADA_C(kk) { _Pragma("unroll") for (int i = 0; i < 2; i++) { \
            int bc = mt * 128 + rS + 64 * i; \
            a_r[i] = ((kk) < 256) \
              ? *(const uint4*)(xh + (((size_t)((bc >> 5) * HCH + h)) << 13) + ((bc & 31) << 8) + (kk) + sgS * 8) \
              : *(const uint4*)(carr + ((size_t)(h * 256 + bc)) * 128 + ((kk) - 256) + sgS * 8); } }
    #define WRITE_A(buf) { _Pragma("unroll") for (int i = 0; i < 2; i++) \
        *(uint4*)&At[buf][(rS + 64 * i) * 40 + sgS * 8] = a_r[i]; }

    // one-shot preloads: KM table, Bc panel (64 t-rows x 128 carry cols, swizzled)
    KMA[tid] = kmg[(size_t)h * 512 + tid];
    KMB[tid] = kmg[(size_t)h * 512 + 256 + tid];
    #pragma unroll
    for (int i = 0; i < 4; i++) {
        int idx = tid + i * 256;            // [0,1024)
        int r = idx >> 4, sg = idx & 15;    // r in [0,64), col granule sg*8
        uint4 v = *(const uint4*)(cT + ((size_t)(h * 256 + nt * 64 + r)) * 128 + sg * 8);
        *(uint4*)&Bc[r * 128 + ((sg * 8) ^ ((r & 7) << 3))] = v;
    }
    LOADA_C(0);
    WRITE_A(0);
    __syncthreads();
    for (int kt = 0; kt < 12; kt++) {
        int cur = kt & 1;
        if (kt < 11) LOADA_C((kt + 1) * 32);
        f16x8 a[4], b[2];
        #pragma unroll
        for (int f = 0; f < 4; f++)
            a[f] = *(const f16x8*)&At[cur][(wm * 64 + f * 16 + lrow) * 40 + koff];
        if (kt < 8) {
            int kk = kt * 32;
            #pragma unroll
            for (int f = 0; f < 2; f++) {
                int t_f = nt * 64 + wn * 32 + f * 16 + lrow;
                int idx0 = 255 - t_f + kk + koff;
                int par = idx0 & 1;
                int dw = idx0 >> 1;
                const uint* kp = par ? KMB : KMA;
                union { uint u[4]; f16x8 v; } bu;
                bu.u[0] = kp[dw]; bu.u[1] = kp[dw + 1]; bu.u[2] = kp[dw + 2]; bu.u[3] = kp[dw + 3];
                b[f] = bu.v;
            }
        } else {
            int cb = kt * 32 - 256 + koff;
            #pragma unroll
            for (int f = 0; f < 2; f++) {
                int r2 = wn * 32 + f * 16 + lrow;
                b[f] = *(const f16x8*)&Bc[r2 * 128 + (cb ^ ((r2 & 7) << 3))];
            }
        }
        #pragma unroll
        for (int fi = 0; fi < 4; fi++)
            #pragma unroll
            for (int fj = 0; fj < 2; fj++)
                acc[fi][fj] = __builtin_amdgcn_mfma_f32_16x16x32_f16(a[fi], b[fj], acc[fi][fj], 0, 0, 0);
        if (kt < 11) {
            WRITE_A(cur ^ 1);
            __syncthreads();
        }
    }
    // fused epilogue: skip + GELU -> f16 store (xh is L2-hot from A-staging)
    float Dh = D[h];
    #pragma unroll
    for (int fi = 0; fi < 4; fi++) {
        #pragma unroll
        for (int fj = 0; fj < 2; fj++) {
            int t = nt * 64 + wn * 32 + fj * 16 + lrow;
            #pragma unroll
            for (int rg = 0; rg < 4; rg++) {
                int bc = mt * 128 + wm * 64 + fi * 16 + quad * 4 + rg;
                size_t base = (((size_t)((bc >> 5) * HCH + h)) << 13) + ((bc & 31) << 8) + t;
                float xv = (float)xh[base];
                float yv = acc[fi][fj][rg] + Dh * xv;
                Yg[base] = (_Float16)gelu_f(yv);
            }
        }
    }
    #undef LOADA_C
    #undef WRITE_A
}

// ---------------- K4: pointwise conv GEMM (W-frags in regs, Yt dbuf) + BN stats ----
__global__ __launch_bounds__(256, 2) void k_pointwise(const _Float16* __restrict__ Yg,
                                                      const _Float16* __restrict__ Wh,
                                                      _Float16* __restrict__ z,
                                                      float* __restrict__ stats) {
    __shared__ _Float16 Yt[2][128 * 40];
    __shared__ float Ls[512];
    int tid = threadIdx.x;
    int b  = blockIdx.x >> 6;
    int l0 = (blockIdx.x & 63) << 7;
    int wave = tid >> 6, lane = tid & 63;
    int wm = wave >> 1, wn = wave & 1;
    int lrow = lane & 15, quad = lane >> 4;
    int koff = quad * 8;
    f32x4 acc[4][4];
    #pragma unroll
    for (int a = 0; a < 4; a++)
        #pragma unroll
        for (int c = 0; c < 4; c++) acc[a][c] = (f32x4){0.f, 0.f, 0.f, 0.f};

    f16x8 a[4][4];
    #pragma unroll
    for (int ks = 0; ks < 4; ks++)
        #pragma unroll
        for (int f = 0; f < 4; f++)
            a[ks][f] = *(const f16x8*)(Wh + (wm * 64 + f * 16 + lrow) * HCH + ks * 32 + koff);

    const int hhS = tid & 31;
    const int lgbase = tid >> 5;    // 0..7; +8*i
    uint4 yv[2];
    #define LOADY(kk) { _Pragma("unroll") for (int i = 0; i < 2; i++) \
        yv[i] = *(const uint4*)(Yg + (((size_t)(b * HCH + (kk) + hhS)) << 13) + l0 + (lgbase + 8 * i) * 8); }
    #define WRITEY(buf) { _Pragma("unroll") for (int i = 0; i < 2; i++) { \
            const _Float16* hv = (const _Float16*)&yv[i]; \
            _Pragma("unroll") for (int j = 0; j < 8; j++) \
                Yt[buf][((lgbase + 8 * i) * 8 + j) * 40 + hhS] = hv[j]; } }

    LOADY(0);
    WRITEY(0);
    __syncthreads();
    for (int kt = 0; kt < 4; kt++) {
        int cur = kt & 1;
        if (kt < 3) LOADY((kt + 1) * 32);
        f16x8 bf[4];
        #pragma unroll
        for (int f = 0; f < 4; f++)
            bf[f] = *(const f16x8*)&Yt[cur][(wn * 64 + f * 16 + lrow) * 40 + koff];
        #pragma unroll
        for (int fi = 0; fi < 4; fi++)
            #pragma unroll
            for (int fj = 0; fj < 4; fj++)
                acc[fi][fj] = __builtin_amdgcn_mfma_f32_16x16x32_f16(a[kt][fi], bf[fj], acc[fi][fj], 0, 0, 0);
        if (kt < 3) {
            WRITEY(cur ^ 1);
            __syncthreads();
        }
    }
    // store z (f16)
    #pragma unroll
    for (int fi = 0; fi < 4; fi++) {
        #pragma unroll
        for (int fj = 0; fj < 4; fj++) {
            int l = l0 + wn * 64 + fj * 16 + lrow;
            #pragma unroll
            for (int rg = 0; rg < 4; rg++) {
                int o = wm * 64 + fi * 16 + quad * 4 + rg;
                z[(((size_t)(b * HCH + o)) << 13) + l] = (_Float16)acc[fi][fj][rg];
            }
        }
    }
    // fused BN stats: 16-lane DPP butterfly, LDS, atomics (fire-and-forget)
    #pragma unroll
    for (int fi = 0; fi < 4; fi++) {
        #pragma unroll
        for (int rg = 0; rg < 4; rg++) {
            float s = 0.f, q = 0.f;
            #pragma unroll
            for (int fj = 0; fj < 4; fj++) {
                float v = acc[fi][fj][rg];
                s += v; q = fmaf(v, v, q);
            }
            DPP_ADD(s, 0xB1); DPP_ADD(s, 0x4E); DPP_ADD(s, 0x141); DPP_ADD(s, 0x140);
            DPP_ADD(q, 0xB1); DPP_ADD(q, 0x4E); DPP_ADD(q, 0x141); DPP_ADD(q, 0x140);
            if (lrow == 0) {
                int olo = fi * 16 + quad * 4 + rg;
                Ls[wave * 64 + olo]       = s;
                Ls[256 + wave * 64 + olo] = q;
            }
        }
    }
    __syncthreads();
    if (tid < HCH) {
        int wmn = tid >> 6;
        int olo = tid & 63;
        float s = Ls[(wmn * 2) * 64 + olo] + Ls[(wmn * 2 + 1) * 64 + olo];
        float q = Ls[256 + (wmn * 2) * 64 + olo] + Ls[256 + (wmn * 2 + 1) * 64 + olo];
        atomicAdd(&stats[tid], s);
        atomicAdd(&stats[HCH + tid], q);
    }
    #undef LOADY
    #undef WRITEY
}

// ---------------- K5: BN normalize + ELU + residual (z f16, residual from xh f16) ----
__global__ __launch_bounds__(256) void k_final(const _Float16* __restrict__ z,
                                               const _Float16* __restrict__ xh,
                                               const float* __restrict__ stats,
                                               const float* __restrict__ gamma,
                                               const float* __restrict__ beta,
                                               float* __restrict__ out) {
    size_t i8 = (size_t)blockIdx.x * 256 + threadIdx.x;   // 1,048,576 total, 8 elems each
    int o = (int)((i8 >> 10) & (HCH - 1));
    const float inv_cnt = 1.f / (float)(BB * LLEN);
    float m   = stats[o] * inv_cnt;
    float var = stats[HCH + o] * inv_cnt - m * m;
    float rs  = rsqrtf(var + 1e-5f);
    float ga  = gamma[o] * rs;
    float bt  = beta[o] - m * ga;
    uint4 zv = ((const uint4*)z)[i8];
    uint4 xv = ((const uint4*)xh)[i8];
    const _Float16* zh = (const _Float16*)&zv;
    const _Float16* xf = (const _Float16*)&xv;
    float4 ra, rb;
    { float t = fmaf((float)zh[0], ga, bt); float e = t > 0.f ? t : (__expf(t) - 1.f); ra.x = e + (float)xf[0]; }
    { float t = fmaf((float)zh[1], ga, bt); float e = t > 0.f ? t : (__expf(t) - 1.f); ra.y = e + (float)xf[1]; }
    { float t = fmaf((float)zh[2], ga, bt); float e = t > 0.f ? t : (__expf(t) - 1.f); ra.z = e + (float)xf[2]; }
    { float t = fmaf((float)zh[3], ga, bt); float e = t > 0.f ? t : (__expf(t) - 1.f); ra.w = e + (float)xf[3]; }
    { float t = fmaf((float)zh[4], ga, bt); float e = t > 0.f ? t : (__expf(t) - 1.f); rb.x = e + (float)xf[4]; }
    { float t = fmaf((float)zh[5], ga, bt); float e = t > 0.f ? t : (__expf(t) - 1.f); rb.y = e + (float)xf[5]; }
    { float t = fmaf((float)zh[6], ga, bt); float e = t > 0.f ? t : (__expf(t) - 1.f); rb.z = e + (float)xf[6]; }
    { float t = fmaf((float)zh[7], ga, bt); float e = t > 0.f ? t : (__expf(t) - 1.f); rb.w = e + (float)xf[7]; }
    ((float4*)out)[2 * i8]     = ra;
    ((float4*)out)[2 * i8 + 1] = rb;
}

extern "C" void kernel_launch(void* const* d_in, const int* in_sizes, int n_in,
                              void* d_out, int out_size, void* d_ws, size_t ws_size,
                              hipStream_t stream) {
    const float* x     = (const float*)d_in[0];
    const float* C_re  = (const float*)d_in[1];
    const float* C_im  = (const float*)d_in[2];
    const float* logA  = (const float*)d_in[3];
    const float* Aim   = (const float*)d_in[4];
    const float* logdt = (const float*)d_in[5];
    const float* D     = (const float*)d_in[6];
    const float* W     = (const float*)d_in[7];
    const float* gamma = (const float*)d_in[8];
    const float* beta  = (const float*)d_in[9];

    float* ws = (float*)d_ws;
    // [0 .. 2097152): eT f16 (dead after k_states_c)
    // [0 .. 4194304): Yg f16 (written by k_conv_g, after eT dead)
    _Float16* eT    = (_Float16*)ws;
    _Float16* Yg    = (_Float16*)ws;
    // [8388608 .. 12582912): zf f16
    _Float16* zf    = (_Float16*)(ws + 8388608);
    // [12582912 .. 14680064): cT f16 (carry-coefficient columns, compact)
    _Float16* cT    = (_Float16*)(ws + 12582912);
    // [14680064 .. 14745600): kmg (128 h x 512 uints)
    uint*     kmg   = (uint*)(ws + 14680064);
    // [16777216 ..): carr f16, Pw, stats, Wh f16, xh f16
    _Float16* carr  = (_Float16*)(ws + 16777216);
    float*    Pw    = ws + 16777216 + 2097152;           // 18874368
    float*    stats = Pw + 8192;                          // 18882560 (256 floats)
    _Float16* Wh    = (_Float16*)(ws + 18882880);         // 16384 f16
    _Float16* xh    = (_Float16*)(ws + 18891072);         // 8.39M f16
    float*    out   = (float*)d_out;

    k_prep     <<<256,  256, 0, stream>>>(C_re, C_im, logA, Aim, logdt, W, cT, kmg, eT, Wh, Pw, stats);
    k_states_c <<<512,  256, 0, stream>>>(x, eT, Pw, xh, carr);
    k_conv_g   <<<1024, 256, 0, stream>>>(xh, kmg, cT, carr, D, Yg);
    k_pointwise<<<512,  256, 0, stream>>>(Yg, Wh, zf, stats);
    k_final    <<<4096, 256, 0, stream>>>(zf, xh, stats, gamma, beta, out);
}